// Round 1
// 490.317 us; speedup vs baseline: 1.0260x; 1.0260x over previous
//
#include <hip/hip_runtime.h>
#include <hip/hip_fp16.h>

#define IN_C  256
#define HID_C 128
#define OUT_C 2
#define BSH   7                    // nodes per bucket = 128
#define NB    128
#define BCAP  6144                 // k_bucket LDS edge capacity (mean 4096)

typedef __attribute__((ext_vector_type(8))) short short8;
typedef __attribute__((ext_vector_type(4))) float float4v;

__device__ __forceinline__ unsigned short f2bf(float f) {   // RNE float->bf16
    unsigned u = __float_as_uint(f);
    unsigned r = 0x7fffu + ((u >> 16) & 1u);
    return (unsigned short)((u + r) >> 16);
}
__device__ __forceinline__ unsigned pk2(float a, float b) {
    return (unsigned)f2bf(a) | ((unsigned)f2bf(b) << 16);
}
// edge record: bits[16:0]=src, bits[31:17]=fp16(w) without sign (w>=0)
__device__ __forceinline__ unsigned enc_edge(int src, float w) {
    unsigned h = (unsigned)(__half_as_ushort(__float2half(w)) & 0x7FFF);
    return (h << 17) | (unsigned)src;
}
__device__ __forceinline__ void dec_edge(unsigned rec, int& s, float& w) {
    s = (int)(rec & 0x1FFFFu);
    __half hh;
    *(unsigned short*)&hh = (unsigned short)(rec >> 17);
    w = __half2float(hh);
}
__device__ __forceinline__ void up8(uint4 p, float* f) {    // 8 bf16 -> f32
    f[0] = __uint_as_float(p.x << 16); f[1] = __uint_as_float(p.x & 0xffff0000u);
    f[2] = __uint_as_float(p.y << 16); f[3] = __uint_as_float(p.y & 0xffff0000u);
    f[4] = __uint_as_float(p.z << 16); f[5] = __uint_as_float(p.z & 0xffff0000u);
    f[6] = __uint_as_float(p.w << 16); f[7] = __uint_as_float(p.w & 0xffff0000u);
}
__device__ __forceinline__ void fma8(float* ac, uint4 p, float w) {
    float t[8]; up8(p, t);
#pragma unroll
    for (int k = 0; k < 8; k++) ac[k] = fmaf(w, t[k], ac[k]);
}

// ---- W1^T bf16 precompute --------------------------------------------------
__global__ void k_wT(const float* __restrict__ W1, unsigned short* __restrict__ w1t) {
    int i = blockIdx.x * 256 + threadIdx.x;     // i = c*256 + k (write-coalesced)
    if (i >= HID_C * IN_C) return;
    int c = i >> 8, k = i & 255;
    w1t[i] = f2bf(W1[(size_t)k * HID_C + c]);
}

// ---- pass 1a: per-wg bucket histogram -> gcnt[b*W + w] ---------------------
__global__ __launch_bounds__(256) void k_count(const int* __restrict__ ei,
                                               int* __restrict__ gcnt,
                                               int E, int K, int W, int CHv) {
    extern __shared__ int lh[];                // K ints
    int w = blockIdx.x, t = threadIdx.x;
    for (int b = t; b < K; b += 256) lh[b] = 0;
    __syncthreads();
    int j0 = w * CHv;
    int j1 = min(j0 + CHv, E);
    for (int j = j0 + t; j < j1; j += 256)
        atomicAdd(&lh[ei[E + j] >> BSH], 1);
    __syncthreads();
    for (int b = t; b < K; b += 256) gcnt[(size_t)b * W + w] = lh[b];
}

// ---- scan: 4096 elems/block ------------------------------------------------
__global__ __launch_bounds__(256) void k_scanA4(const int* __restrict__ cnt,
                                                int* __restrict__ excl,
                                                int* __restrict__ bsum, int n) {
    __shared__ int ss[256];
    int t = threadIdx.x;
    int base = blockIdx.x * 4096 + t * 16;
    int v[16]; int s = 0;
#pragma unroll
    for (int q = 0; q < 16; q++) { v[q] = (base + q < n) ? cnt[base + q] : 0; s += v[q]; }
    ss[t] = s;
    __syncthreads();
    for (int d = 1; d < 256; d <<= 1) {
        int x = (t >= d) ? ss[t - d] : 0;
        __syncthreads();
        ss[t] += x;
        __syncthreads();
    }
    int pre = (t == 0) ? 0 : ss[t - 1];
    if (t == 255) bsum[blockIdx.x] = ss[255];
    int run = pre;
#pragma unroll
    for (int q = 0; q < 16; q++) { if (base + q < n) excl[base + q] = run; run += v[q]; }
}

__global__ __launch_bounds__(256) void k_scanB(int* __restrict__ bsum, int nb) {
    __shared__ int ss[256];
    int t = threadIdx.x;
    int v = (t < nb) ? bsum[t] : 0;
    ss[t] = v;
    __syncthreads();
    for (int d = 1; d < 256; d <<= 1) {
        int x = (t >= d) ? ss[t - d] : 0;
        __syncthreads();
        ss[t] += x;
        __syncthreads();
    }
    if (t < nb) bsum[t] = ss[t] - v;   // exclusive
}

__global__ void k_scanC4(int* __restrict__ gpos, const int* __restrict__ bsum, int n) {
    int i = blockIdx.x * 256 + threadIdx.x;
    if (i < n) gpos[i] += bsum[i >> 12];
}

// ---- pass 1c: place edges into ebuf, bucket-grouped ------------------------
// ebuf entry: {src | ldst<<17, w_f32}   (src < 2^17, ldst < 128)
__global__ __launch_bounds__(256) void k_place(const int* __restrict__ ei,
                                               const float* __restrict__ w,
                                               const int* __restrict__ gpos,
                                               int2* __restrict__ ebuf,
                                               int E, int K, int W, int CHv) {
    extern __shared__ int lc[];                // K cursors
    int wg = blockIdx.x, t = threadIdx.x;
    for (int b = t; b < K; b += 256) lc[b] = gpos[(size_t)b * W + wg];
    __syncthreads();
    int j0 = wg * CHv;
    int j1 = min(j0 + CHv, E);
    for (int j = j0 + t; j < j1; j += 256) {
        int s = ei[j], d = ei[E + j];
        float wv = w[j];
        int pos = atomicAdd(&lc[d >> BSH], 1);
        ebuf[pos] = make_int2(s | ((d & (NB - 1)) << 17), __float_as_int(wv));
    }
}

// ---- pass 2: per-bucket fine CSR + dinv; packed 4B edata (RAW weight) ------
__global__ __launch_bounds__(256) void k_bucket(const int2* __restrict__ ebuf,
                                                const int* __restrict__ gpos,
                                                unsigned* __restrict__ epack,
                                                int* __restrict__ rowptr,
                                                float* __restrict__ dinv,
                                                int W, int K, int E, int N) {
    __shared__ int2 ls[BCAP];
    __shared__ int lh[NB], lex[NB], lc[NB];
    int b = blockIdx.x, t = threadIdx.x;
    int base = gpos[(size_t)b * W];
    int next = (b + 1 < K) ? gpos[(size_t)(b + 1) * W] : E;
    int cnt = next - base;
    for (int i = t; i < NB; i += 256) lh[i] = 0;
    __syncthreads();
    if (cnt <= BCAP) {
        for (int j = t; j < cnt; j += 256)                     // pass A: hist
            atomicAdd(&lh[(ebuf[base + j].x >> 17) & (NB - 1)], 1);
        __syncthreads();
        if (t == 0) {
            int run = 0;
            for (int i = 0; i < NB; i++) { lex[i] = run; lc[i] = run; run += lh[i]; }
        }
        __syncthreads();
        for (int j = t; j < cnt; j += 256) {                   // pass B: LDS sort
            int2 e = ebuf[base + j];
            int pos = atomicAdd(&lc[(e.x >> 17) & (NB - 1)], 1);
            ls[pos] = make_int2(e.x & 0x1FFFF, e.y);
        }
        __syncthreads();
        for (int j = t; j < cnt; j += 256) {                   // coalesced 4B out
            int2 e = ls[j];
            epack[base + j] = enc_edge(e.x, __int_as_float(e.y));
        }
        for (int r = t; r < NB; r += 256) {
            int node = b * NB + r;
            if (node < N) {
                rowptr[node] = base + lex[r];
                float s = 1.0f;                                // self-loop weight
                int rb = lex[r], re = rb + lh[r];
                for (int j = rb; j < re; j++) s += __int_as_float(ls[j].y);
                dinv[node] = s > 0.f ? rsqrtf(s) : 0.f;
            }
        }
    } else {                                                   // fallback (overflow)
        for (int j = base + t; j < next; j += 256)
            atomicAdd(&lh[(ebuf[j].x >> 17) & (NB - 1)], 1);
        __syncthreads();
        if (t == 0) {
            int run = 0;
            for (int i = 0; i < NB; i++) { lex[i] = run; lc[i] = run; run += lh[i]; }
        }
        __syncthreads();
        for (int j = base + t; j < next; j += 256) {
            int2 e = ebuf[j];
            int pos = base + atomicAdd(&lc[(e.x >> 17) & (NB - 1)], 1);
            epack[pos] = enc_edge(e.x & 0x1FFFF, __int_as_float(e.y));
        }
        __syncthreads();
        for (int r = t; r < NB; r += 256) {
            int node = b * NB + r;
            if (node < N) {
                int rb = base + lex[r], re = rb + lh[r];
                rowptr[node] = rb;
                float s = 1.0f;
                for (int j = rb; j < re; j++) {
                    int ss; float wv;
                    dec_edge(epack[j], ss, wv);
                    s += wv;
                }
                dinv[node] = s > 0.f ? rsqrtf(s) : 0.f;
            }
        }
    }
    if (b == K - 1 && t == 0) rowptr[N] = E;
}

// ---- GEMM1 (MFMA bf16): h1b[N,128] = dinv[.] * (x[N,256] @ W1) -------------
#define XS_LD 36
#define WT_LD 260
__global__ __launch_bounds__(256) void k_gemm1(const float* __restrict__ x,
                                               const unsigned short* __restrict__ w1t,
                                               const float* __restrict__ dinv,
                                               unsigned short* __restrict__ h1b, int n) {
    __shared__ __align__(16) unsigned short wt[HID_C * WT_LD];
    __shared__ __align__(16) unsigned short xs[64 * XS_LD];
    int tid  = threadIdx.x;
    int row0 = blockIdx.x * 64;
    for (int it = 0; it < 16; it++) {
        int idx = it * 256 + tid;
        int c = idx >> 5, kc = idx & 31;
        uint4 v = *(const uint4*)(w1t + (size_t)c * IN_C + kc * 8);
        uint2* dst = (uint2*)(wt + c * WT_LD + kc * 8);
        dst[0] = make_uint2(v.x, v.y);
        dst[1] = make_uint2(v.z, v.w);
    }
    int wv = tid >> 6, ln = tid & 63;
    int m = ln & 15, quad = ln >> 4;
    float4v acc[8];
#pragma unroll
    for (int ct = 0; ct < 8; ct++) acc[ct] = (float4v){0.f, 0.f, 0.f, 0.f};

    for (int k0 = 0; k0 < IN_C; k0 += 32) {
        __syncthreads();
        {
            int r = tid >> 2, s4 = tid & 3;
            int gr = row0 + r; if (gr >= n) gr = n - 1;
            const float4* px = (const float4*)(x + (size_t)gr * IN_C + k0 + s4 * 8);
            float4 a = px[0], bq = px[1];
            uint2* d = (uint2*)(xs + r * XS_LD + s4 * 8);
            d[0] = make_uint2(pk2(a.x, a.y), pk2(a.z, a.w));
            d[1] = make_uint2(pk2(bq.x, bq.y), pk2(bq.z, bq.w));
        }
        __syncthreads();
        union { uint2 u[2]; short8 v; } af;
        const uint2* pa = (const uint2*)(xs + (wv * 16 + m) * XS_LD + quad * 8);
        af.u[0] = pa[0]; af.u[1] = pa[1];
#pragma unroll
        for (int ct = 0; ct < 8; ct++) {
            union { uint2 u[2]; short8 v; } bf;
            const uint2* pb = (const uint2*)(wt + (ct * 16 + m) * WT_LD + k0 + quad * 8);
            bf.u[0] = pb[0]; bf.u[1] = pb[1];
            acc[ct] = __builtin_amdgcn_mfma_f32_16x16x32_bf16(af.v, bf.v, acc[ct], 0, 0, 0);
        }
    }
    __syncthreads();
    // fold dinv[row] into the stored features: h1b' = dinv * (x@W1)
    float4 dv = *(const float4*)(dinv + row0 + wv * 16 + quad * 4);
    const float* dvf = (const float*)&dv;
    unsigned short* ot = wt;
#pragma unroll
    for (int ct = 0; ct < 8; ct++)
#pragma unroll
        for (int r = 0; r < 4; r++)
            ot[(wv * 16 + quad * 4 + r) * 136 + ct * 16 + m] = f2bf(acc[ct][r] * dvf[r]);
    __syncthreads();
#pragma unroll
    for (int p = 0; p < 4; p++) {
        int idx = p * 256 + tid;
        int r = idx >> 4, c8 = idx & 15;
        if (row0 + r < n)
            *(uint4*)(h1b + (size_t)(row0 + r) * HID_C + c8 * 8) =
                *(const uint4*)(ot + r * 136 + c8 * 8);
    }
}

// ---- layer-1 aggregation + fused gemm2 -------------------------------------
// 16 lanes per edge (dwordx4 gathers), 4 edges per load inst, 8 edges/iter.
// h1b holds dinv[s]*h1[s]; epack holds raw w; epilogue multiplies by dinv[d].
__global__ __launch_bounds__(256) void k_agg1(const int* __restrict__ rowptr,
                                              const unsigned* __restrict__ epack,
                                              const unsigned short* __restrict__ h1b,
                                              const float* __restrict__ dinv,
                                              const float* __restrict__ b1,
                                              const float* __restrict__ W2,
                                              float* __restrict__ h2, int n) {
    int wid  = (blockIdx.x * 256 + threadIdx.x) >> 6;
    int lane = threadIdx.x & 63;
    if (wid >= n) return;
    int q   = lane >> 4;          // edge slot within wave (0..3)
    int c16 = lane & 15;          // 16B chunk of the 256B feature row
    int beg = rowptr[wid], end = rowptr[wid + 1];
    float ac[8];
#pragma unroll
    for (int k = 0; k < 8; k++) ac[k] = 0.f;
    int j = beg;
    for (; j + 8 <= end; j += 8) {            // 8 edges, 2 gathers in flight
        unsigned r0 = epack[j + q];
        unsigned r1 = epack[j + 4 + q];
        int s0, s1; float w0, w1;
        dec_edge(r0, s0, w0);
        dec_edge(r1, s1, w1);
        uint4 p0 = *(const uint4*)(h1b + (size_t)s0 * HID_C + c16 * 8);
        uint4 p1 = *(const uint4*)(h1b + (size_t)s1 * HID_C + c16 * 8);
        fma8(ac, p0, w0);
        fma8(ac, p1, w1);
    }
    for (; j < end; j += 4) {                  // exec-masked tail (no waste)
        int jj = j + q;
        if (jj < end) {
            unsigned r0 = epack[jj];
            int s0; float w0;
            dec_edge(r0, s0, w0);
            uint4 p0 = *(const uint4*)(h1b + (size_t)s0 * HID_C + c16 * 8);
            fma8(ac, p0, w0);
        }
    }
    // combine the 4 edge slots (quads hold same channels)
#pragma unroll
    for (int k = 0; k < 8; k++) {
        ac[k] += __shfl_xor(ac[k], 16);
        ac[k] += __shfl_xor(ac[k], 32);
    }
    // epilogue: + self-loop, *dinv[d], +b1, relu, dot W2, butterfly, store h2'
    float di = dinv[wid];
    uint4 ps = *(const uint4*)(h1b + (size_t)wid * HID_C + c16 * 8);
    float sf[8]; up8(ps, sf);
    float4 ba = *(const float4*)(b1 + c16 * 8);
    float4 bb = *(const float4*)(b1 + c16 * 8 + 4);
    const float* bap = (const float*)&ba;
    const float* bbp = (const float*)&bb;
    float o[8];
#pragma unroll
    for (int k = 0; k < 4; k++) o[k]     = fmaxf(fmaf(di, ac[k] + sf[k], bap[k]), 0.f);
#pragma unroll
    for (int k = 0; k < 4; k++) o[k + 4] = fmaxf(fmaf(di, ac[k + 4] + sf[k + 4], bbp[k]), 0.f);
    const float4* wp = (const float4*)(W2 + 16 * c16);   // rows 8*c16..8*c16+7
    float4 wa = wp[0], wb = wp[1], wc = wp[2], wd = wp[3];
    float s0 = o[0] * wa.x + o[1] * wa.z + o[2] * wb.x + o[3] * wb.z
             + o[4] * wc.x + o[5] * wc.z + o[6] * wd.x + o[7] * wd.z;
    float s1 = o[0] * wa.y + o[1] * wa.w + o[2] * wb.y + o[3] * wb.w
             + o[4] * wc.y + o[5] * wc.w + o[6] * wd.y + o[7] * wd.w;
#pragma unroll
    for (int d = 8; d > 0; d >>= 1) {
        s0 += __shfl_xor(s0, d);
        s1 += __shfl_xor(s1, d);
    }
    if (lane == 0)
        ((float2*)h2)[wid] = make_float2(di * s0, di * s1);   // h2' = dinv*H2
}

// ---- layer-2 aggregation: wave/node, lanes over edges ----------------------
__global__ __launch_bounds__(256) void k_agg2(const int* __restrict__ rowptr,
                                              const unsigned* __restrict__ epack,
                                              const float* __restrict__ h2,
                                              const float* __restrict__ dinv,
                                              const float* __restrict__ b2,
                                              float* __restrict__ out, int n) {
    int wid  = (blockIdx.x * 256 + threadIdx.x) >> 6;
    int lane = threadIdx.x & 63;
    if (wid >= n) return;
    int beg = rowptr[wid], end = rowptr[wid + 1];
    float sx = 0.f, sy = 0.f;
    for (int j = beg + lane; j < end; j += 64) {
        int es; float nm;
        dec_edge(epack[j], es, nm);
        float2 v = ((const float2*)h2)[es];
        sx = fmaf(nm, v.x, sx);
        sy = fmaf(nm, v.y, sy);
    }
#pragma unroll
    for (int d = 32; d > 0; d >>= 1) {
        sx += __shfl_xor(sx, d);
        sy += __shfl_xor(sy, d);
    }
    if (lane == 0) {
        float di = dinv[wid];
        float2 hv = ((const float2*)h2)[wid];   // already dinv[wid]*H2[wid]
        ((float2*)out)[wid] = make_float2(b2[0] + di * (sx + hv.x),
                                          b2[1] + di * (sy + hv.y));
    }
}

extern "C" void kernel_launch(void* const* d_in, const int* in_sizes, int n_in,
                              void* d_out, int out_size, void* d_ws, size_t ws_size,
                              hipStream_t stream) {
    const float* x  = (const float*)d_in[0];
    const int*   ei = (const int*)d_in[1];   // [2,E] int32
    const float* ew = (const float*)d_in[2];
    const float* W1 = (const float*)d_in[3];
    const float* b1 = (const float*)d_in[4];
    const float* W2 = (const float*)d_in[5];
    const float* b2 = (const float*)d_in[6];
    float* out = (float*)d_out;

    int N = in_sizes[0] / IN_C;
    int E = in_sizes[2];
    int K = (N + NB - 1) >> BSH;             // buckets (782)
    int W = 256;                             // pass-1 workgroups = CU count
    int CHv = (E + W - 1) / W;               // edges per workgroup
    int KW = K * W;

    char* ws = (char*)d_ws;
    float* dinv   = (float*)ws; ws += (size_t)N * 4;
    int*   rowptr = (int*)ws;   ws += (size_t)(N + 1) * 4 + 4 + 8;  // +8: 16B-align later bufs
    int*   gcnt   = (int*)ws;   ws += (size_t)KW * 4;
    int*   bsum   = (int*)ws;   ws += 1024;
    int2*  ebuf   = (int2*)ws;  ws += (size_t)E * 8;
    unsigned* epack = (unsigned*)ws; ws += (size_t)E * 4;
    unsigned short* w1t = (unsigned short*)ws; ws += (size_t)HID_C * IN_C * 2;
    unsigned short* h1b = (unsigned short*)ws; ws += (size_t)N * HID_C * 2;
    float* h2     = (float*)ws; ws += (size_t)N * OUT_C * 4;

    int nb_s4 = (KW + 4095) / 4096;
    int nb_sc = (KW + 255) / 256;
    int nb_w  = (N * 64 + 255) / 256;
    size_t lds_k = (size_t)K * 4;            // ~3.1 KB dynamic LDS

    k_wT    <<<(HID_C * IN_C + 255) / 256, 256, 0, stream>>>(W1, w1t);
    k_count <<<W, 256, lds_k, stream>>>(ei, gcnt, E, K, W, CHv);
    k_scanA4<<<nb_s4, 256, 0, stream>>>(gcnt, gcnt, bsum, KW);
    k_scanB <<<1, 256, 0, stream>>>(bsum, nb_s4);
    k_scanC4<<<nb_sc, 256, 0, stream>>>(gcnt, bsum, KW);
    k_place <<<W, 256, lds_k, stream>>>(ei, ew, gcnt, ebuf, E, K, W, CHv);
    k_bucket<<<K, 256, 0, stream>>>(ebuf, gcnt, epack, rowptr, dinv, W, K, E, N);
    k_gemm1 <<<(N + 63) / 64, 256, 0, stream>>>(x, w1t, dinv, h1b, N);
    k_agg1  <<<nb_w, 256, 0, stream>>>(rowptr, epack, h1b, dinv, b1, W2, h2, N);
    k_agg2  <<<nb_w, 256, 0, stream>>>(rowptr, epack, h2, dinv, b2, out, N);
}